// Round 1
// baseline (573.500 us; speedup 1.0000x reference)
//
#include <hip/hip_runtime.h>
#include <hip/hip_bf16.h>
#include <stdint.h>

#define BATCH 8
#define SEQ   2048
#define DIM   1024

typedef unsigned short u16;
typedef __attribute__((ext_vector_type(8))) short short8;
typedef __attribute__((ext_vector_type(4))) float f32x4;
typedef __attribute__((ext_vector_type(4))) int   int4v;

__device__ __forceinline__ u16 f2bf(float x){
  union { float f; uint32_t u; } c; c.f = x;
  uint32_t u = c.u;
  uint32_t r = u + 0x7fffu + ((u >> 16) & 1u);
  return (u16)(r >> 16);
}
__device__ __forceinline__ float bf2f(u16 s){
  union { uint32_t u; float f; } c; c.u = ((uint32_t)s) << 16;
  return c.f;
}

// ---------- V transpose + split:  Vt[d][s] = V[s][d]  (hi/lo bf16) ----------
__global__ __launch_bounds__(256) void k_convert_vt(const float* __restrict__ V,
                                                    u16* __restrict__ Vth,
                                                    u16* __restrict__ Vtl,
                                                    int b0){
  __shared__ float tile[32][33];
  int z = blockIdx.z;
  const float* Vb = V + (size_t)(b0 + z) * SEQ * DIM;
  u16* Vthb = Vth + (size_t)z * DIM * SEQ;
  u16* Vtlb = Vtl + (size_t)z * DIM * SEQ;
  int s0 = blockIdx.x * 32, d0 = blockIdx.y * 32;
  int tx = threadIdx.x, ty = threadIdx.y;
  #pragma unroll
  for (int i = 0; i < 4; i++){
    tile[ty + i*8][tx] = Vb[(size_t)(s0 + ty + i*8) * DIM + d0 + tx];
  }
  __syncthreads();
  #pragma unroll
  for (int i = 0; i < 4; i++){
    int dr = ty + i*8;
    float x = tile[tx][dr];
    u16 h = f2bf(x);
    u16 l = f2bf(x - bf2f(h));
    size_t off = (size_t)(d0 + dr) * SEQ + s0 + tx;
    Vthb[off] = h;
    Vtlb[off] = l;
  }
}

#define BM 128
#define BN 128
#define BK 32

// ---------- GEMM1: P = (Q @ K^T) * scale, stored as bf16 hi/lo ----------
__global__ __launch_bounds__(256,2) void k_gemm1(const float* __restrict__ Q,
                                                 const float* __restrict__ K,
                                                 u16* __restrict__ Ph,
                                                 u16* __restrict__ Pl,
                                                 int b0){
  __shared__ __align__(16) u16 Ah[BM][BK], Al[BM][BK], Bh[BN][BK], Bl[BN][BK];
  int z = blockIdx.z;
  const float* Qb = Q + (size_t)(b0 + z) * SEQ * DIM;
  const float* Kb = K + (size_t)(b0 + z) * SEQ * DIM;
  u16* Phb = Ph + (size_t)z * SEQ * SEQ;
  u16* Plb = Pl + (size_t)z * SEQ * SEQ;

  int t = threadIdx.x;
  int lane = t & 63, wave = t >> 6;
  int wm = (wave & 1) * 64, wn = (wave >> 1) * 64;
  int fr = lane & 15;
  int kg = (lane >> 4) * 8;

  f32x4 acc[4][4] = {};
  const float* Abase = Qb + (size_t)(blockIdx.x * BM) * DIM;
  const float* Bbase = Kb + (size_t)(blockIdx.y * BN) * DIM;

  for (int k0 = 0; k0 < DIM; k0 += BK){
    #pragma unroll
    for (int i = 0; i < 4; i++){
      int c   = t + i * 256;       // 1024 float4 chunks per 128x32 tile
      int row = c >> 3;
      int cq  = (c & 7) << 2;
      f32x4 va = *(const f32x4*)(Abase + (size_t)row * DIM + k0 + cq);
      f32x4 vb = *(const f32x4*)(Bbase + (size_t)row * DIM + k0 + cq);
      u16 ha[4], la[4], hb[4], lb[4];
      #pragma unroll
      for (int j = 0; j < 4; j++){
        ha[j] = f2bf(va[j]); la[j] = f2bf(va[j] - bf2f(ha[j]));
        hb[j] = f2bf(vb[j]); lb[j] = f2bf(vb[j] - bf2f(hb[j]));
      }
      uint32_t* pah = (uint32_t*)&Ah[row][cq];
      pah[0] = (uint32_t)ha[0] | ((uint32_t)ha[1] << 16);
      pah[1] = (uint32_t)ha[2] | ((uint32_t)ha[3] << 16);
      uint32_t* pal = (uint32_t*)&Al[row][cq];
      pal[0] = (uint32_t)la[0] | ((uint32_t)la[1] << 16);
      pal[1] = (uint32_t)la[2] | ((uint32_t)la[3] << 16);
      uint32_t* pbh = (uint32_t*)&Bh[row][cq];
      pbh[0] = (uint32_t)hb[0] | ((uint32_t)hb[1] << 16);
      pbh[1] = (uint32_t)hb[2] | ((uint32_t)hb[3] << 16);
      uint32_t* pbl = (uint32_t*)&Bl[row][cq];
      pbl[0] = (uint32_t)lb[0] | ((uint32_t)lb[1] << 16);
      pbl[1] = (uint32_t)lb[2] | ((uint32_t)lb[3] << 16);
    }
    __syncthreads();

    short8 fah[4], fal[4], fbh[4], fbl[4];
    #pragma unroll
    for (int mi = 0; mi < 4; mi++){
      fah[mi] = *(const short8*)&Ah[wm + mi*16 + fr][kg];
      fal[mi] = *(const short8*)&Al[wm + mi*16 + fr][kg];
      fbh[mi] = *(const short8*)&Bh[wn + mi*16 + fr][kg];
      fbl[mi] = *(const short8*)&Bl[wn + mi*16 + fr][kg];
    }
    #pragma unroll
    for (int mi = 0; mi < 4; mi++){
      #pragma unroll
      for (int ni = 0; ni < 4; ni++){
        acc[mi][ni] = __builtin_amdgcn_mfma_f32_16x16x32_bf16(fah[mi], fbh[ni], acc[mi][ni], 0,0,0);
        acc[mi][ni] = __builtin_amdgcn_mfma_f32_16x16x32_bf16(fah[mi], fbl[ni], acc[mi][ni], 0,0,0);
        acc[mi][ni] = __builtin_amdgcn_mfma_f32_16x16x32_bf16(fal[mi], fbh[ni], acc[mi][ni], 0,0,0);
      }
    }
    __syncthreads();
  }

  const float scale = 0.03125f;   // 1/sqrt(1024)
  int cr = (lane >> 4) * 4, cc = lane & 15;
  #pragma unroll
  for (int mi = 0; mi < 4; mi++){
    int gr = blockIdx.x * BM + wm + mi*16 + cr;
    #pragma unroll
    for (int ni = 0; ni < 4; ni++){
      int gc = blockIdx.y * BN + wn + ni*16 + cc;
      #pragma unroll
      for (int r = 0; r < 4; r++){
        float x = acc[mi][ni][r] * scale;
        u16 h = f2bf(x);
        u16 l = f2bf(x - bf2f(h));
        size_t off = (size_t)(gr + r) * SEQ + gc;
        Phb[off] = h;
        Plb[off] = l;
      }
    }
  }
}

// ---------- GEMM2: O = P @ V  (A = P hi/lo, B = Vt hi/lo), fp32 out ----------
__global__ __launch_bounds__(256,2) void k_gemm2(const u16* __restrict__ Ph,
                                                 const u16* __restrict__ Pl,
                                                 const u16* __restrict__ Vth,
                                                 const u16* __restrict__ Vtl,
                                                 float* __restrict__ Out,
                                                 int b0){
  __shared__ __align__(16) u16 Ah[BM][BK], Al[BM][BK], Bh[BN][BK], Bl[BN][BK];
  int z = blockIdx.z;
  const u16* Phb  = Ph  + (size_t)z * SEQ * SEQ;
  const u16* Plb  = Pl  + (size_t)z * SEQ * SEQ;
  const u16* Vthb = Vth + (size_t)z * DIM * SEQ;
  const u16* Vtlb = Vtl + (size_t)z * DIM * SEQ;
  float* Ob = Out + (size_t)(b0 + z) * SEQ * DIM;

  int t = threadIdx.x;
  int lane = t & 63, wave = t >> 6;
  int wm = (wave & 1) * 64, wn = (wave >> 1) * 64;
  int fr = lane & 15;
  int kg = (lane >> 4) * 8;

  f32x4 acc[4][4] = {};
  const u16* Abase  = Phb  + (size_t)(blockIdx.x * BM) * SEQ;
  const u16* Albase = Plb  + (size_t)(blockIdx.x * BM) * SEQ;
  const u16* Bbase  = Vthb + (size_t)(blockIdx.y * BN) * SEQ;
  const u16* Blbase = Vtlb + (size_t)(blockIdx.y * BN) * SEQ;

  for (int k0 = 0; k0 < SEQ; k0 += BK){
    #pragma unroll
    for (int i = 0; i < 2; i++){
      int c   = t + i * 256;     // 512 chunks of 8 bf16 (16B)
      int row = c >> 2;
      int ce  = (c & 3) << 3;
      *(int4v*)&Ah[row][ce] = *(const int4v*)(Abase  + (size_t)row * SEQ + k0 + ce);
      *(int4v*)&Al[row][ce] = *(const int4v*)(Albase + (size_t)row * SEQ + k0 + ce);
      *(int4v*)&Bh[row][ce] = *(const int4v*)(Bbase  + (size_t)row * SEQ + k0 + ce);
      *(int4v*)&Bl[row][ce] = *(const int4v*)(Blbase + (size_t)row * SEQ + k0 + ce);
    }
    __syncthreads();

    short8 fah[4], fal[4], fbh[4], fbl[4];
    #pragma unroll
    for (int mi = 0; mi < 4; mi++){
      fah[mi] = *(const short8*)&Ah[wm + mi*16 + fr][kg];
      fal[mi] = *(const short8*)&Al[wm + mi*16 + fr][kg];
      fbh[mi] = *(const short8*)&Bh[wn + mi*16 + fr][kg];
      fbl[mi] = *(const short8*)&Bl[wn + mi*16 + fr][kg];
    }
    #pragma unroll
    for (int mi = 0; mi < 4; mi++){
      #pragma unroll
      for (int ni = 0; ni < 4; ni++){
        acc[mi][ni] = __builtin_amdgcn_mfma_f32_16x16x32_bf16(fah[mi], fbh[ni], acc[mi][ni], 0,0,0);
        acc[mi][ni] = __builtin_amdgcn_mfma_f32_16x16x32_bf16(fah[mi], fbl[ni], acc[mi][ni], 0,0,0);
        acc[mi][ni] = __builtin_amdgcn_mfma_f32_16x16x32_bf16(fal[mi], fbh[ni], acc[mi][ni], 0,0,0);
      }
    }
    __syncthreads();
  }

  int cr = (lane >> 4) * 4, cc = lane & 15;
  #pragma unroll
  for (int mi = 0; mi < 4; mi++){
    int gr = blockIdx.x * BM + wm + mi*16 + cr;
    #pragma unroll
    for (int ni = 0; ni < 4; ni++){
      int gc = blockIdx.y * BN + wn + ni*16 + cc;
      #pragma unroll
      for (int r = 0; r < 4; r++){
        Ob[(size_t)(gr + r) * DIM + gc] = acc[mi][ni][r];
      }
    }
  }
}

// ---------- row softmax over D=1024, in place on d_out ----------
__global__ __launch_bounds__(256) void k_softmax(float* __restrict__ O){
  float* p = O + (size_t)blockIdx.x * DIM;
  int t = threadIdx.x;
  int lane = t & 63, wave = t >> 6;
  f32x4 v = *(f32x4*)(p + t*4);
  float m = fmaxf(fmaxf(v[0], v[1]), fmaxf(v[2], v[3]));
  #pragma unroll
  for (int o = 32; o > 0; o >>= 1) m = fmaxf(m, __shfl_xor(m, o));
  __shared__ float rmax[4], rsum[4];
  if (lane == 0) rmax[wave] = m;
  __syncthreads();
  m = fmaxf(fmaxf(rmax[0], rmax[1]), fmaxf(rmax[2], rmax[3]));
  float e0 = expf(v[0]-m), e1 = expf(v[1]-m), e2 = expf(v[2]-m), e3 = expf(v[3]-m);
  float s = e0 + e1 + e2 + e3;
  #pragma unroll
  for (int o = 32; o > 0; o >>= 1) s += __shfl_xor(s, o);
  if (lane == 0) rsum[wave] = s;
  __syncthreads();
  s = rsum[0] + rsum[1] + rsum[2] + rsum[3];
  float inv = 1.0f / s;
  f32x4 r = { e0*inv, e1*inv, e2*inv, e3*inv };
  *(f32x4*)(p + t*4) = r;
}

extern "C" void kernel_launch(void* const* d_in, const int* in_sizes, int n_in,
                              void* d_out, int out_size, void* d_ws, size_t ws_size,
                              hipStream_t stream){
  const float* Q = (const float*)d_in[0];
  const float* K = (const float*)d_in[1];
  const float* V = (const float*)d_in[2];
  float* Out = (float*)d_out;
  u16* w = (u16*)d_ws;

  const size_t vtN = (size_t)DIM * SEQ;   // per-batch Vt elems per array
  const size_t pN  = (size_t)SEQ * SEQ;   // per-batch P  elems per array

  dim3 blk(256);
  dim3 cblk(32, 8);
  dim3 cgrid(SEQ/32, DIM/32, 1);
  dim3 g1(SEQ/BM, SEQ/BN, 1);
  dim3 g2(SEQ/BM, DIM/BN, 1);

  size_t needFull = (16*vtN + 16*pN) * sizeof(u16);  // ~192 MB
  size_t needMid  = (16*vtN +  2*pN) * sizeof(u16);  // ~80 MB
  if (ws_size >= needFull){
    u16* Vth = w;            u16* Vtl = w + 8*vtN;
    u16* Ph  = w + 16*vtN;   u16* Pl  = Ph + 8*pN;
    dim3 cg = cgrid; cg.z = BATCH;
    k_convert_vt<<<cg, cblk, 0, stream>>>(V, Vth, Vtl, 0);
    dim3 gg1 = g1; gg1.z = BATCH;
    k_gemm1<<<gg1, blk, 0, stream>>>(Q, K, Ph, Pl, 0);
    dim3 gg2 = g2; gg2.z = BATCH;
    k_gemm2<<<gg2, blk, 0, stream>>>(Ph, Pl, Vth, Vtl, Out, 0);
  } else if (ws_size >= needMid){
    u16* Vth = w;            u16* Vtl = w + 8*vtN;
    u16* Ph  = w + 16*vtN;   u16* Pl  = Ph + pN;
    dim3 cg = cgrid; cg.z = BATCH;
    k_convert_vt<<<cg, cblk, 0, stream>>>(V, Vth, Vtl, 0);
    for (int b = 0; b < BATCH; b++){
      k_gemm1<<<g1, blk, 0, stream>>>(Q, K, Ph, Pl, b);
      k_gemm2<<<g2, blk, 0, stream>>>(Ph, Pl, Vth + (size_t)b*vtN, Vtl + (size_t)b*vtN, Out, b);
    }
  } else {
    u16* Vth = w;            u16* Vtl = w + vtN;
    u16* Ph  = w + 2*vtN;    u16* Pl  = Ph + pN;
    for (int b = 0; b < BATCH; b++){
      k_convert_vt<<<cgrid, cblk, 0, stream>>>(V, Vth, Vtl, b);
      k_gemm1<<<g1, blk, 0, stream>>>(Q, K, Ph, Pl, b);
      k_gemm2<<<g2, blk, 0, stream>>>(Ph, Pl, Vth, Vtl, Out, b);
    }
  }
  k_softmax<<<dim3(BATCH*SEQ), blk, 0, stream>>>(Out);
}

// Round 2
// 522.948 us; speedup vs baseline: 1.0967x; 1.0967x over previous
//
#include <hip/hip_runtime.h>
#include <hip/hip_bf16.h>
#include <stdint.h>

#define BATCH 8
#define SEQ   2048
#define DIM   1024

typedef unsigned short u16;
typedef __attribute__((ext_vector_type(8))) short short8;
typedef __attribute__((ext_vector_type(4))) float f32x4;
typedef __attribute__((ext_vector_type(4))) unsigned short us4;

__device__ __forceinline__ u16 f2bf(float x){
  union { float f; uint32_t u; } c; c.f = x;
  uint32_t u = c.u;
  uint32_t r = u + 0x7fffu + ((u >> 16) & 1u);
  return (u16)(r >> 16);
}
__device__ __forceinline__ float bf2f(u16 s){
  union { uint32_t u; float f; } c; c.u = ((uint32_t)s) << 16;
  return c.f;
}

// async global->LDS, 16B per lane. LDS dest is wave-uniform base + lane*16.
__device__ __forceinline__ void gload16(const void* g, void* l){
  __builtin_amdgcn_global_load_lds(
      (const __attribute__((address_space(1))) void*)g,
      (__attribute__((address_space(3))) void*)l, 16, 0, 0);
}

// ---------- split fp32 [R][1024] -> u16 [R][2048] rows packed [hi|lo] ----------
__global__ __launch_bounds__(256) void k_split(const float* __restrict__ src,
                                               u16* __restrict__ dst, int nchunk){
  for (int i = blockIdx.x*blockDim.x + threadIdx.x; i < nchunk; i += gridDim.x*blockDim.x){
    int r = i >> 8;            // 256 chunks of 4 floats per 1024-row
    int c = (i & 255) << 2;
    f32x4 v = *(const f32x4*)(src + (size_t)r*DIM + c);
    us4 h, l;
    #pragma unroll
    for (int j = 0; j < 4; j++){
      u16 hh = f2bf(v[j]);
      h[j] = hh;
      l[j] = f2bf(v[j] - bf2f(hh));
    }
    u16* d = dst + (size_t)r*(2*DIM) + c;
    *(us4*)d         = h;
    *(us4*)(d + DIM) = l;
  }
}

// ---------- V transpose + split: Vts[d][s](hi), Vts[d][2048+s](lo), row width 4096 ----------
__global__ __launch_bounds__(256) void k_convert_vt(const float* __restrict__ V,
                                                    u16* __restrict__ Vts){
  __shared__ float tile[32][33];
  int z = blockIdx.z;
  const float* Vb = V + (size_t)z * SEQ * DIM;
  u16* Vtb = Vts + (size_t)z * DIM * (2*SEQ);
  int s0 = blockIdx.x * 32, d0 = blockIdx.y * 32;
  int tx = threadIdx.x, ty = threadIdx.y;
  #pragma unroll
  for (int i = 0; i < 4; i++){
    tile[ty + i*8][tx] = Vb[(size_t)(s0 + ty + i*8) * DIM + d0 + tx];
  }
  __syncthreads();
  #pragma unroll
  for (int i = 0; i < 4; i++){
    int dr = ty + i*8;
    float x = tile[tx][dr];
    u16 h = f2bf(x);
    u16 l = f2bf(x - bf2f(h));
    size_t off = (size_t)(d0 + dr) * (2*SEQ) + s0 + tx;
    Vtb[off]       = h;
    Vtb[off + SEQ] = l;
  }
}

// ---------- GEMM C = A * B^T with hi/lo split operands ----------
// A: [2048][2*KB] u16 rows packed [hi|lo]; B: [N_][2*KB] u16 packed [hi|lo].
// SPLITOUT=1: C = acc*1/32 stored split into u16 [2048][2*SEQ] ([hi|lo]).
// SPLITOUT=0: C = acc stored fp32 [2048][N_].
template<int N_, int KB, int SPLITOUT>
__global__ __launch_bounds__(256,2) void k_gemm(const u16* __restrict__ A,
                                                const u16* __restrict__ B,
                                                void* __restrict__ Cout,
                                                size_t aStride, size_t bStride, size_t cStride){
  constexpr int LA = 2*KB;
  __shared__ __align__(16) u16 Ah[128*32], Al[128*32], Bh[128*32], Bl[128*32];

  const u16* Ab = A + (size_t)blockIdx.z * aStride;
  const u16* Bb = B + (size_t)blockIdx.z * bStride;

  int t = threadIdx.x, lane = t & 63, w = t >> 6;
  int wm = (w & 1) * 64, wn = (w >> 1) * 64;
  int fr = lane & 15, kg = (lane >> 4) * 8;

  // staging geometry: chunk = w*2+o covers rows [chunk*16, chunk*16+16)
  // lane covers row chunk*16 + (lane>>2), elems (lane&3)*8 .. +8  (16B)
  int srow = lane >> 2;
  int scol = (lane & 3) * 8;

  const u16* aBase = Ab + ((size_t)blockIdx.x*128) * LA + scol;
  const u16* bBase = Bb + ((size_t)blockIdx.y*128) * LA + scol;

  f32x4 acc[4][4] = {};

  for (int k0 = 0; k0 < KB; k0 += 32){
    #pragma unroll
    for (int o = 0; o < 2; o++){
      int chunk = w*2 + o;
      size_t rOff = (size_t)(chunk*16 + srow) * LA + k0;
      const u16* ga = aBase + rOff;
      const u16* gb = bBase + rOff;
      int le = chunk * 512;            // elems; HW adds lane*16 bytes
      gload16(ga,      Ah + le);
      gload16(ga + KB, Al + le);
      gload16(gb,      Bh + le);
      gload16(gb + KB, Bl + le);
    }
    __syncthreads();

    short8 fah[4], fal[4], fbh[4], fbl[4];
    #pragma unroll
    for (int mi = 0; mi < 4; mi++){
      fah[mi] = *(const short8*)&Ah[(wm + mi*16 + fr)*32 + kg];
      fal[mi] = *(const short8*)&Al[(wm + mi*16 + fr)*32 + kg];
      fbh[mi] = *(const short8*)&Bh[(wn + mi*16 + fr)*32 + kg];
      fbl[mi] = *(const short8*)&Bl[(wn + mi*16 + fr)*32 + kg];
    }
    #pragma unroll
    for (int mi = 0; mi < 4; mi++){
      #pragma unroll
      for (int ni = 0; ni < 4; ni++){
        acc[mi][ni] = __builtin_amdgcn_mfma_f32_16x16x32_bf16(fah[mi], fbh[ni], acc[mi][ni], 0,0,0);
        acc[mi][ni] = __builtin_amdgcn_mfma_f32_16x16x32_bf16(fah[mi], fbl[ni], acc[mi][ni], 0,0,0);
        acc[mi][ni] = __builtin_amdgcn_mfma_f32_16x16x32_bf16(fal[mi], fbh[ni], acc[mi][ni], 0,0,0);
      }
    }
    __syncthreads();
  }

  int cr = (lane >> 4) * 4, cc = lane & 15;
  if (SPLITOUT){
    u16* Cb = (u16*)Cout + (size_t)blockIdx.z * cStride;
    const float scale = 0.03125f;   // 1/sqrt(1024)
    #pragma unroll
    for (int mi = 0; mi < 4; mi++){
      int gr = blockIdx.x*128 + wm + mi*16 + cr;
      #pragma unroll
      for (int ni = 0; ni < 4; ni++){
        int gc = blockIdx.y*128 + wn + ni*16 + cc;
        #pragma unroll
        for (int r = 0; r < 4; r++){
          float x = acc[mi][ni][r] * scale;
          u16 h = f2bf(x);
          u16 l = f2bf(x - bf2f(h));
          size_t off = (size_t)(gr + r) * (2*SEQ) + gc;
          Cb[off]       = h;
          Cb[off + SEQ] = l;
        }
      }
    }
  } else {
    float* Cb = (float*)Cout + (size_t)blockIdx.z * cStride;
    #pragma unroll
    for (int mi = 0; mi < 4; mi++){
      int gr = blockIdx.x*128 + wm + mi*16 + cr;
      #pragma unroll
      for (int ni = 0; ni < 4; ni++){
        int gc = blockIdx.y*128 + wn + ni*16 + cc;
        #pragma unroll
        for (int r = 0; r < 4; r++){
          Cb[(size_t)(gr + r) * N_ + gc] = acc[mi][ni][r];
        }
      }
    }
  }
}

// ---------- row softmax over D=1024, in place on d_out ----------
__global__ __launch_bounds__(256) void k_softmax(float* __restrict__ O){
  float* p = O + (size_t)blockIdx.x * DIM;
  int t = threadIdx.x;
  int lane = t & 63, wave = t >> 6;
  f32x4 v = *(f32x4*)(p + t*4);
  float m = fmaxf(fmaxf(v[0], v[1]), fmaxf(v[2], v[3]));
  #pragma unroll
  for (int o = 32; o > 0; o >>= 1) m = fmaxf(m, __shfl_xor(m, o));
  __shared__ float rmax[4], rsum[4];
  if (lane == 0) rmax[wave] = m;
  __syncthreads();
  m = fmaxf(fmaxf(rmax[0], rmax[1]), fmaxf(rmax[2], rmax[3]));
  float e0 = expf(v[0]-m), e1 = expf(v[1]-m), e2 = expf(v[2]-m), e3 = expf(v[3]-m);
  float s = e0 + e1 + e2 + e3;
  #pragma unroll
  for (int o = 32; o > 0; o >>= 1) s += __shfl_xor(s, o);
  if (lane == 0) rsum[wave] = s;
  __syncthreads();
  s = rsum[0] + rsum[1] + rsum[2] + rsum[3];
  float inv = 1.0f / s;
  f32x4 r = { e0*inv, e1*inv, e2*inv, e3*inv };
  *(f32x4*)(p + t*4) = r;
}

extern "C" void kernel_launch(void* const* d_in, const int* in_sizes, int n_in,
                              void* d_out, int out_size, void* d_ws, size_t ws_size,
                              hipStream_t stream){
  const float* Q = (const float*)d_in[0];
  const float* K = (const float*)d_in[1];
  const float* V = (const float*)d_in[2];
  float* Out = (float*)d_out;
  u16* w = (u16*)d_ws;

  const size_t QsB  = (size_t)SEQ * (2*DIM);   // 4.19M elems / batch
  const size_t KsB  = QsB;
  const size_t VtsB = (size_t)DIM * (2*SEQ);   // 4.19M
  const size_t PsB  = (size_t)SEQ * (2*SEQ);   // 8.39M
  const size_t perB = (QsB + KsB + VtsB + PsB) * sizeof(u16);  // ~41.9 MB

  int NB = 8;
  while (NB > 1 && (size_t)NB * perB > ws_size) NB >>= 1;

  for (int b0 = 0; b0 < BATCH; b0 += NB){
    u16* Qs  = w;
    u16* Ks  = Qs + (size_t)NB * QsB;
    u16* Vts = Ks + (size_t)NB * KsB;
    u16* Ps  = Vts + (size_t)NB * VtsB;

    int nchunk = NB * SEQ * (DIM/4);
    k_split<<<dim3(2048), dim3(256), 0, stream>>>(Q + (size_t)b0*SEQ*DIM, Qs, nchunk);
    k_split<<<dim3(2048), dim3(256), 0, stream>>>(K + (size_t)b0*SEQ*DIM, Ks, nchunk);
    k_convert_vt<<<dim3(SEQ/32, DIM/32, NB), dim3(32,8), 0, stream>>>(V + (size_t)b0*SEQ*DIM, Vts);

    // GEMM1: P = (Q K^T)/32  -> split u16 [2048][4096]
    k_gemm<SEQ, DIM, 1><<<dim3(16,16,NB), dim3(256), 0, stream>>>(
        Qs, Ks, Ps, QsB, KsB, PsB);
    // GEMM2: O = P V  -> fp32 [2048][1024]
    k_gemm<DIM, SEQ, 0><<<dim3(16,8,NB), dim3(256), 0, stream>>>(
        Ps, Vts, Out + (size_t)b0*SEQ*DIM, PsB, VtsB, (size_t)SEQ*DIM);
  }
  k_softmax<<<dim3(BATCH*SEQ), dim3(256), 0, stream>>>(Out);
}

// Round 3
// 354.948 us; speedup vs baseline: 1.6157x; 1.4733x over previous
//
#include <hip/hip_runtime.h>
#include <hip/hip_bf16.h>
#include <stdint.h>

#define BATCH 8
#define SEQ   2048
#define DIM   1024

typedef unsigned short u16;
typedef __attribute__((ext_vector_type(8))) short short8;
typedef __attribute__((ext_vector_type(4))) float f32x4;
typedef __attribute__((ext_vector_type(4))) unsigned short us4;

__device__ __forceinline__ u16 f2bf(float x){
  union { float f; uint32_t u; } c; c.f = x;
  uint32_t u = c.u;
  uint32_t r = u + 0x7fffu + ((u >> 16) & 1u);
  return (u16)(r >> 16);
}
__device__ __forceinline__ float bf2f(u16 s){
  union { uint32_t u; float f; } c; c.u = ((uint32_t)s) << 16;
  return c.f;
}

// async global->LDS, 16B per lane. LDS dest is wave-uniform base + lane*16.
__device__ __forceinline__ void gload16(const void* g, void* l){
  __builtin_amdgcn_global_load_lds(
      (const __attribute__((address_space(1))) void*)g,
      (__attribute__((address_space(3))) void*)l, 16, 0, 0);
}

// ---------- split fp32 [R][1024] -> u16 [R][2048] rows packed [hi|lo] ----------
__global__ __launch_bounds__(256) void k_split(const float* __restrict__ src,
                                               u16* __restrict__ dst, int nchunk){
  for (int i = blockIdx.x*blockDim.x + threadIdx.x; i < nchunk; i += gridDim.x*blockDim.x){
    int r = i >> 8;            // 256 chunks of 4 floats per 1024-row
    int c = (i & 255) << 2;
    f32x4 v = *(const f32x4*)(src + (size_t)r*DIM + c);
    us4 h, l;
    #pragma unroll
    for (int j = 0; j < 4; j++){
      u16 hh = f2bf(v[j]);
      h[j] = hh;
      l[j] = f2bf(v[j] - bf2f(hh));
    }
    u16* d = dst + (size_t)r*(2*DIM) + c;
    *(us4*)d         = h;
    *(us4*)(d + DIM) = l;
  }
}

// ---------- transpose + split: X[s][d] -> Xt[d][s](hi), Xt[d][2048+s](lo) ----------
__global__ __launch_bounds__(256) void k_convert_vt(const float* __restrict__ V,
                                                    u16* __restrict__ Vts){
  __shared__ float tile[32][33];
  int z = blockIdx.z;
  const float* Vb = V + (size_t)z * SEQ * DIM;
  u16* Vtb = Vts + (size_t)z * DIM * (2*SEQ);
  int s0 = blockIdx.x * 32, d0 = blockIdx.y * 32;
  int tx = threadIdx.x, ty = threadIdx.y;
  #pragma unroll
  for (int i = 0; i < 4; i++){
    tile[ty + i*8][tx] = Vb[(size_t)(s0 + ty + i*8) * DIM + d0 + tx];
  }
  __syncthreads();
  #pragma unroll
  for (int i = 0; i < 4; i++){
    int dr = ty + i*8;
    float x = tile[tx][dr];
    u16 h = f2bf(x);
    u16 l = f2bf(x - bf2f(h));
    size_t off = (size_t)(d0 + dr) * (2*SEQ) + s0 + tx;
    Vtb[off]       = h;
    Vtb[off + SEQ] = l;
  }
}

// ---------- GEMM C = A * B^T with hi/lo split operands ----------
// A: [M][2*KB] u16 rows packed [hi|lo]; B: [N_][2*KB] u16 packed [hi|lo].
// SPLITOUT=1: C = acc*1/32 stored split into u16 [M][2*N_] ([hi|lo]).
// SPLITOUT=0: C = acc stored fp32 [M][N_].
template<int N_, int KB, int SPLITOUT>
__global__ __launch_bounds__(256,2) void k_gemm(const u16* __restrict__ A,
                                                const u16* __restrict__ B,
                                                void* __restrict__ Cout,
                                                size_t aStride, size_t bStride, size_t cStride){
  constexpr int LA = 2*KB;
  __shared__ __align__(16) u16 Ah[128*32], Al[128*32], Bh[128*32], Bl[128*32];

  const u16* Ab = A + (size_t)blockIdx.z * aStride;
  const u16* Bb = B + (size_t)blockIdx.z * bStride;

  int t = threadIdx.x, lane = t & 63, w = t >> 6;
  int wm = (w & 1) * 64, wn = (w >> 1) * 64;
  int fr = lane & 15, kg = (lane >> 4) * 8;

  int srow = lane >> 2;
  int scol = (lane & 3) * 8;

  const u16* aBase = Ab + ((size_t)blockIdx.x*128) * LA + scol;
  const u16* bBase = Bb + ((size_t)blockIdx.y*128) * LA + scol;

  f32x4 acc[4][4] = {};

  for (int k0 = 0; k0 < KB; k0 += 32){
    #pragma unroll
    for (int o = 0; o < 2; o++){
      int chunk = w*2 + o;
      size_t rOff = (size_t)(chunk*16 + srow) * LA + k0;
      const u16* ga = aBase + rOff;
      const u16* gb = bBase + rOff;
      int le = chunk * 512;            // elems; HW adds lane*16 bytes
      gload16(ga,      Ah + le);
      gload16(ga + KB, Al + le);
      gload16(gb,      Bh + le);
      gload16(gb + KB, Bl + le);
    }
    __syncthreads();

    short8 fah[4], fal[4], fbh[4], fbl[4];
    #pragma unroll
    for (int mi = 0; mi < 4; mi++){
      fah[mi] = *(const short8*)&Ah[(wm + mi*16 + fr)*32 + kg];
      fal[mi] = *(const short8*)&Al[(wm + mi*16 + fr)*32 + kg];
      fbh[mi] = *(const short8*)&Bh[(wn + mi*16 + fr)*32 + kg];
      fbl[mi] = *(const short8*)&Bl[(wn + mi*16 + fr)*32 + kg];
    }
    #pragma unroll
    for (int mi = 0; mi < 4; mi++){
      #pragma unroll
      for (int ni = 0; ni < 4; ni++){
        acc[mi][ni] = __builtin_amdgcn_mfma_f32_16x16x32_bf16(fah[mi], fbh[ni], acc[mi][ni], 0,0,0);
        acc[mi][ni] = __builtin_amdgcn_mfma_f32_16x16x32_bf16(fah[mi], fbl[ni], acc[mi][ni], 0,0,0);
        acc[mi][ni] = __builtin_amdgcn_mfma_f32_16x16x32_bf16(fal[mi], fbh[ni], acc[mi][ni], 0,0,0);
      }
    }
    __syncthreads();
  }

  int cr = (lane >> 4) * 4, cc = lane & 15;
  if (SPLITOUT){
    u16* Cb = (u16*)Cout + (size_t)blockIdx.z * cStride;
    const float scale = 0.03125f;   // 1/sqrt(1024)
    #pragma unroll
    for (int mi = 0; mi < 4; mi++){
      int gr = blockIdx.x*128 + wm + mi*16 + cr;
      #pragma unroll
      for (int ni = 0; ni < 4; ni++){
        int gc = blockIdx.y*128 + wn + ni*16 + cc;
        #pragma unroll
        for (int r = 0; r < 4; r++){
          float x = acc[mi][ni][r] * scale;
          u16 h = f2bf(x);
          u16 l = f2bf(x - bf2f(h));
          size_t off = (size_t)(gr + r) * (2*N_) + gc;
          Cb[off]      = h;
          Cb[off + N_] = l;
        }
      }
    }
  } else {
    float* Cb = (float*)Cout + (size_t)blockIdx.z * cStride;
    #pragma unroll
    for (int mi = 0; mi < 4; mi++){
      int gr = blockIdx.x*128 + wm + mi*16 + cr;
      #pragma unroll
      for (int ni = 0; ni < 4; ni++){
        int gc = blockIdx.y*128 + wn + ni*16 + cc;
        #pragma unroll
        for (int r = 0; r < 4; r++){
          Cb[(size_t)(gr + r) * N_ + gc] = acc[mi][ni][r];
        }
      }
    }
  }
}

// ---------- row softmax over D=1024, in place on d_out ----------
__global__ __launch_bounds__(256) void k_softmax(float* __restrict__ O){
  float* p = O + (size_t)blockIdx.x * DIM;
  int t = threadIdx.x;
  int lane = t & 63, wave = t >> 6;
  f32x4 v = *(f32x4*)(p + t*4);
  float m = fmaxf(fmaxf(v[0], v[1]), fmaxf(v[2], v[3]));
  #pragma unroll
  for (int o = 32; o > 0; o >>= 1) m = fmaxf(m, __shfl_xor(m, o));
  __shared__ float rmax[4], rsum[4];
  if (lane == 0) rmax[wave] = m;
  __syncthreads();
  m = fmaxf(fmaxf(rmax[0], rmax[1]), fmaxf(rmax[2], rmax[3]));
  float e0 = expf(v[0]-m), e1 = expf(v[1]-m), e2 = expf(v[2]-m), e3 = expf(v[3]-m);
  float s = e0 + e1 + e2 + e3;
  #pragma unroll
  for (int o = 32; o > 0; o >>= 1) s += __shfl_xor(s, o);
  if (lane == 0) rsum[wave] = s;
  __syncthreads();
  s = rsum[0] + rsum[1] + rsum[2] + rsum[3];
  float inv = 1.0f / s;
  f32x4 r = { e0*inv, e1*inv, e2*inv, e3*inv };
  *(f32x4*)(p + t*4) = r;
}

extern "C" void kernel_launch(void* const* d_in, const int* in_sizes, int n_in,
                              void* d_out, int out_size, void* d_ws, size_t ws_size,
                              hipStream_t stream){
  const float* Q = (const float*)d_in[0];
  const float* K = (const float*)d_in[1];
  const float* V = (const float*)d_in[2];
  float* Out = (float*)d_out;
  u16* w = (u16*)d_ws;

  const size_t QsB = (size_t)SEQ * (2*DIM);   // 4.19M elems / batch
  const size_t KtB = (size_t)DIM * (2*SEQ);   // 4.19M
  const size_t VtB = KtB;
  const size_t WsB = (size_t)DIM * (2*DIM);   // 2.10M

  dim3 blk(256);
  dim3 cblk(32, 8);

  const size_t need1 = 8 * (QsB + KtB + VtB + WsB) * sizeof(u16);  // ~235 MB
  const size_t need2 = 8 * (KtB + VtB + WsB) * sizeof(u16);        // ~168 MB
  const size_t need3 = (QsB + KtB + VtB + WsB) * sizeof(u16);      // ~29 MB

  if (ws_size >= need1){
    u16* Qs = w;
    u16* Kt = Qs + 8*QsB;
    u16* Vt = Kt + 8*KtB;
    u16* Ws = Vt + 8*VtB;
    k_split<<<dim3(2048), blk, 0, stream>>>(Q, Qs, 8*SEQ*(DIM/4));
    k_convert_vt<<<dim3(SEQ/32, DIM/32, 8), cblk, 0, stream>>>(K, Kt);
    k_convert_vt<<<dim3(SEQ/32, DIM/32, 8), cblk, 0, stream>>>(V, Vt);
    // Wt = (V^T K)/32  -> split u16 [1024][2048] per batch   (Wt = W^T, W = K^T V)
    k_gemm<DIM, SEQ, 1><<<dim3(8, 8, 8), blk, 0, stream>>>(Vt, Kt, Ws, VtB, KtB, WsB);
    // O = Q W = Qs * Wt^T -> fp32 [2048][1024] per batch
    k_gemm<DIM, DIM, 0><<<dim3(16, 8, 8), blk, 0, stream>>>(Qs, Ws, Out, QsB, WsB, (size_t)SEQ*DIM);
  } else if (ws_size >= need2){
    // reuse: Qs overwrites Kt/Vt region after GEMM-A has consumed them
    u16* Kt = w;
    u16* Vt = Kt + 8*KtB;
    u16* Ws = Vt + 8*VtB;
    u16* Qs = w;                         // aliases Kt region (sequential stream order)
    k_convert_vt<<<dim3(SEQ/32, DIM/32, 8), cblk, 0, stream>>>(K, Kt);
    k_convert_vt<<<dim3(SEQ/32, DIM/32, 8), cblk, 0, stream>>>(V, Vt);
    k_gemm<DIM, SEQ, 1><<<dim3(8, 8, 8), blk, 0, stream>>>(Vt, Kt, Ws, VtB, KtB, WsB);
    k_split<<<dim3(2048), blk, 0, stream>>>(Q, Qs, 8*SEQ*(DIM/4));
    k_gemm<DIM, DIM, 0><<<dim3(16, 8, 8), blk, 0, stream>>>(Qs, Ws, Out, QsB, WsB, (size_t)SEQ*DIM);
  } else {
    // per-batch fallback
    u16* Qs = w;
    u16* Kt = Qs + QsB;
    u16* Vt = Kt + KtB;
    u16* Ws = Vt + VtB;
    (void)need3;
    for (int b = 0; b < BATCH; b++){
      const size_t inOff = (size_t)b * SEQ * DIM;
      k_split<<<dim3(1024), blk, 0, stream>>>(Q + inOff, Qs, SEQ*(DIM/4));
      k_convert_vt<<<dim3(SEQ/32, DIM/32, 1), cblk, 0, stream>>>(K + inOff, Kt);
      k_convert_vt<<<dim3(SEQ/32, DIM/32, 1), cblk, 0, stream>>>(V + inOff, Vt);
      k_gemm<DIM, SEQ, 1><<<dim3(8, 8, 1), blk, 0, stream>>>(Vt, Kt, Ws, VtB, KtB, WsB);
      k_gemm<DIM, DIM, 0><<<dim3(16, 8, 1), blk, 0, stream>>>(Qs, Ws, Out + inOff, QsB, WsB, (size_t)SEQ*DIM);
    }
  }
  k_softmax<<<dim3(BATCH*SEQ), blk, 0, stream>>>(Out);
}

// Round 4
// 312.348 us; speedup vs baseline: 1.8361x; 1.1364x over previous
//
#include <hip/hip_runtime.h>
#include <hip/hip_bf16.h>
#include <stdint.h>

#define BATCH 8
#define SEQ   2048
#define DIM   1024

typedef unsigned short u16;
typedef __attribute__((ext_vector_type(8))) short short8;
typedef __attribute__((ext_vector_type(4))) float f32x4;
typedef __attribute__((ext_vector_type(4))) unsigned short us4;

__device__ __forceinline__ u16 f2bf(float x){
  union { float f; uint32_t u; } c; c.f = x;
  uint32_t u = c.u;
  uint32_t r = u + 0x7fffu + ((u >> 16) & 1u);
  return (u16)(r >> 16);
}
__device__ __forceinline__ float bf2f(u16 s){
  union { uint32_t u; float f; } c; c.u = ((uint32_t)s) << 16;
  return c.f;
}

// async global->LDS, 16B per lane. LDS dest is wave-uniform base + lane*16.
__device__ __forceinline__ void gload16(const void* g, void* l){
  __builtin_amdgcn_global_load_lds(
      (const __attribute__((address_space(1))) void*)g,
      (__attribute__((address_space(3))) void*)l, 16, 0, 0);
}

// ---------- split fp32 [R][1024] -> u16 [R][2048] rows packed [hi|lo] ----------
__global__ __launch_bounds__(256) void k_split(const float* __restrict__ src,
                                               u16* __restrict__ dst, int nchunk){
  for (int i = blockIdx.x*blockDim.x + threadIdx.x; i < nchunk; i += gridDim.x*blockDim.x){
    int r = i >> 8;
    int c = (i & 255) << 2;
    f32x4 v = *(const f32x4*)(src + (size_t)r*DIM + c);
    us4 h, l;
    #pragma unroll
    for (int j = 0; j < 4; j++){
      u16 hh = f2bf(v[j]);
      h[j] = hh;
      l[j] = f2bf(v[j] - bf2f(hh));
    }
    u16* d = dst + (size_t)r*(2*DIM) + c;
    *(us4*)d         = h;
    *(us4*)(d + DIM) = l;
  }
}

// ---------- transpose + split: X[s][d] -> Xt[d][s](hi), Xt[d][2048+s](lo) ----------
__global__ __launch_bounds__(256) void k_convert_vt(const float* __restrict__ V,
                                                    u16* __restrict__ Vts){
  __shared__ float tile[32][33];
  int z = blockIdx.z;
  const float* Vb = V + (size_t)z * SEQ * DIM;
  u16* Vtb = Vts + (size_t)z * DIM * (2*SEQ);
  int s0 = blockIdx.x * 32, d0 = blockIdx.y * 32;
  int tx = threadIdx.x, ty = threadIdx.y;
  #pragma unroll
  for (int i = 0; i < 4; i++){
    tile[ty + i*8][tx] = Vb[(size_t)(s0 + ty + i*8) * DIM + d0 + tx];
  }
  __syncthreads();
  #pragma unroll
  for (int i = 0; i < 4; i++){
    int dr = ty + i*8;
    float x = tile[tx][dr];
    u16 h = f2bf(x);
    u16 l = f2bf(x - bf2f(h));
    size_t off = (size_t)(d0 + dr) * (2*SEQ) + s0 + tx;
    Vtb[off]       = h;
    Vtb[off + SEQ] = l;
  }
}

// ---------- GEMM C = A * B^T, hi/lo split operands, BK=64, swizzled LDS ----------
// A: [M][2*KB] u16 rows packed [hi|lo]; B: [N_][2*KB] u16 packed [hi|lo].
// 1-D grid, XCD-aware: 8 XCDs; per XCD, per batch, an RX x RY tile rectangle.
// SPLITOUT=1: C = acc/32 stored split u16 [M][2*N_]. SPLITOUT=0: C = acc fp32 [M][N_].
template<int N_, int KB, int SPLITOUT, int BX, int RX, int RY>
__global__ __launch_bounds__(256,2) void k_gemm(const u16* __restrict__ A,
                                                const u16* __restrict__ B,
                                                void* __restrict__ Cout,
                                                size_t aStride, size_t bStride, size_t cStride){
  constexpr int LA = 2*KB;
  __shared__ __align__(16) u16 Ah[128*64], Al[128*64], Bh[128*64], Bl[128*64];

  // XCD rectangle remap (bijective; grid = 8 * nz * RX*RY blocks)
  int orig = blockIdx.x;
  int xcd = orig & 7;
  int idx = orig >> 3;
  constexpr int RN = RX * RY;
  int z  = idx / RN;
  int r  = idx % RN;
  int bx = (xcd % (BX/RX)) * RX + (r % RX);
  int by = (xcd / (BX/RX)) * RY + (r / RX);

  const u16* Ab = A + (size_t)z * aStride;
  const u16* Bb = B + (size_t)z * bStride;

  int t = threadIdx.x, lane = t & 63, w = t >> 6;
  int wm = (w & 1) * 64, wn = (w >> 1) * 64;
  int fr = lane & 15;

  // staging: chunk c covers rows [c*8, c*8+8); lane covers row c*8+(lane>>3),
  // fetches global 8-elem slot ((lane&7) ^ (lane>>3)) -> LDS slot (lane&7) (linear).
  int srow    = lane >> 3;
  int srcSlot = ((lane & 7) ^ (lane >> 3)) * 8;

  const u16* aBase = Ab + ((size_t)bx*128) * LA + srcSlot;
  const u16* bBase = Bb + ((size_t)by*128) * LA + srcSlot;

  // fragment read slots (XOR matches staging): global slot ksub*4+(lane>>4), row&7 = lane&7
  int rdSlot0 = (((0*4) + (lane >> 4)) ^ (lane & 7)) * 8;
  int rdSlot1 = (((1*4) + (lane >> 4)) ^ (lane & 7)) * 8;

  f32x4 acc[4][4] = {};

  for (int k0 = 0; k0 < KB; k0 += 64){
    #pragma unroll
    for (int j = 0; j < 4; j++){
      int c = w*4 + j;
      size_t rOff = (size_t)(c*8 + srow) * LA + k0;
      const u16* ga = aBase + rOff;
      const u16* gb = bBase + rOff;
      int le = c * 512;              // u16 elems; HW adds lane*16 bytes
      gload16(ga,      Ah + le);
      gload16(ga + KB, Al + le);
      gload16(gb,      Bh + le);
      gload16(gb + KB, Bl + le);
    }
    __syncthreads();

    #pragma unroll
    for (int ksub = 0; ksub < 2; ksub++){
      int rs = ksub ? rdSlot1 : rdSlot0;
      short8 fah[4], fal[4], fbh[4], fbl[4];
      #pragma unroll
      for (int mi = 0; mi < 4; mi++){
        fah[mi] = *(const short8*)&Ah[(wm + mi*16 + fr)*64 + rs];
        fal[mi] = *(const short8*)&Al[(wm + mi*16 + fr)*64 + rs];
        fbh[mi] = *(const short8*)&Bh[(wn + mi*16 + fr)*64 + rs];
        fbl[mi] = *(const short8*)&Bl[(wn + mi*16 + fr)*64 + rs];
      }
      #pragma unroll
      for (int mi = 0; mi < 4; mi++){
        #pragma unroll
        for (int ni = 0; ni < 4; ni++){
          acc[mi][ni] = __builtin_amdgcn_mfma_f32_16x16x32_bf16(fah[mi], fbh[ni], acc[mi][ni], 0,0,0);
          acc[mi][ni] = __builtin_amdgcn_mfma_f32_16x16x32_bf16(fah[mi], fbl[ni], acc[mi][ni], 0,0,0);
          acc[mi][ni] = __builtin_amdgcn_mfma_f32_16x16x32_bf16(fal[mi], fbh[ni], acc[mi][ni], 0,0,0);
        }
      }
    }
    __syncthreads();
  }

  int cr = (lane >> 4) * 4, cc = lane & 15;
  if (SPLITOUT){
    u16* Cb = (u16*)Cout + (size_t)z * cStride;
    const float scale = 0.03125f;   // 1/sqrt(1024)
    #pragma unroll
    for (int mi = 0; mi < 4; mi++){
      int gr = bx*128 + wm + mi*16 + cr;
      #pragma unroll
      for (int ni = 0; ni < 4; ni++){
        int gc = by*128 + wn + ni*16 + cc;
        #pragma unroll
        for (int rr = 0; rr < 4; rr++){
          float x = acc[mi][ni][rr] * scale;
          u16 h = f2bf(x);
          u16 l = f2bf(x - bf2f(h));
          size_t off = (size_t)(gr + rr) * (2*N_) + gc;
          Cb[off]      = h;
          Cb[off + N_] = l;
        }
      }
    }
  } else {
    float* Cb = (float*)Cout + (size_t)z * cStride;
    #pragma unroll
    for (int mi = 0; mi < 4; mi++){
      int gr = bx*128 + wm + mi*16 + cr;
      #pragma unroll
      for (int ni = 0; ni < 4; ni++){
        int gc = by*128 + wn + ni*16 + cc;
        #pragma unroll
        for (int rr = 0; rr < 4; rr++){
          Cb[(size_t)(gr + rr) * N_ + gc] = acc[mi][ni][rr];
        }
      }
    }
  }
}

// ---------- row softmax over D=1024, in place on d_out ----------
__global__ __launch_bounds__(256) void k_softmax(float* __restrict__ O){
  float* p = O + (size_t)blockIdx.x * DIM;
  int t = threadIdx.x;
  int lane = t & 63, wave = t >> 6;
  f32x4 v = *(f32x4*)(p + t*4);
  float m = fmaxf(fmaxf(v[0], v[1]), fmaxf(v[2], v[3]));
  #pragma unroll
  for (int o = 32; o > 0; o >>= 1) m = fmaxf(m, __shfl_xor(m, o));
  __shared__ float rmax[4], rsum[4];
  if (lane == 0) rmax[wave] = m;
  __syncthreads();
  m = fmaxf(fmaxf(rmax[0], rmax[1]), fmaxf(rmax[2], rmax[3]));
  float e0 = expf(v[0]-m), e1 = expf(v[1]-m), e2 = expf(v[2]-m), e3 = expf(v[3]-m);
  float s = e0 + e1 + e2 + e3;
  #pragma unroll
  for (int o = 32; o > 0; o >>= 1) s += __shfl_xor(s, o);
  if (lane == 0) rsum[wave] = s;
  __syncthreads();
  s = rsum[0] + rsum[1] + rsum[2] + rsum[3];
  float inv = 1.0f / s;
  f32x4 rv = { e0*inv, e1*inv, e2*inv, e3*inv };
  *(f32x4*)(p + t*4) = rv;
}

extern "C" void kernel_launch(void* const* d_in, const int* in_sizes, int n_in,
                              void* d_out, int out_size, void* d_ws, size_t ws_size,
                              hipStream_t stream){
  const float* Q = (const float*)d_in[0];
  const float* K = (const float*)d_in[1];
  const float* V = (const float*)d_in[2];
  float* Out = (float*)d_out;
  u16* w = (u16*)d_ws;

  const size_t QsB = (size_t)SEQ * (2*DIM);
  const size_t KtB = (size_t)DIM * (2*SEQ);
  const size_t VtB = KtB;
  const size_t WsB = (size_t)DIM * (2*DIM);

  dim3 blk(256);
  dim3 cblk(32, 8);

  const size_t need1 = 8 * (QsB + KtB + VtB + WsB) * sizeof(u16);  // ~235 MB
  const size_t need2 = 8 * (KtB + VtB + WsB) * sizeof(u16);        // ~168 MB

  if (ws_size >= need1){
    u16* Qs = w;
    u16* Kt = Qs + 8*QsB;
    u16* Vt = Kt + 8*KtB;
    u16* Ws = Vt + 8*VtB;
    k_split<<<dim3(2048), blk, 0, stream>>>(Q, Qs, 8*SEQ*(DIM/4));
    k_convert_vt<<<dim3(SEQ/32, DIM/32, 8), cblk, 0, stream>>>(K, Kt);
    k_convert_vt<<<dim3(SEQ/32, DIM/32, 8), cblk, 0, stream>>>(V, Vt);
    // GEMM-A: Wt = (V^T K)/32 -> split u16 [1024][2048]/batch.  grid 8x8x8 = 512
    k_gemm<DIM, SEQ, 1, 8, 2, 4><<<dim3(512), blk, 0, stream>>>(Vt, Kt, Ws, VtB, KtB, WsB);
    // GEMM-B: O = Qs * Wt^T -> fp32 [2048][1024]/batch.  grid 16x8x8 = 1024
    k_gemm<DIM, DIM, 0, 16, 4, 4><<<dim3(1024), blk, 0, stream>>>(Qs, Ws, Out, QsB, WsB, (size_t)SEQ*DIM);
  } else if (ws_size >= need2){
    u16* Kt = w;
    u16* Vt = Kt + 8*KtB;
    u16* Ws = Vt + 8*VtB;
    u16* Qs = w;                         // reuses Kt/Vt region after GEMM-A (stream-ordered)
    k_convert_vt<<<dim3(SEQ/32, DIM/32, 8), cblk, 0, stream>>>(K, Kt);
    k_convert_vt<<<dim3(SEQ/32, DIM/32, 8), cblk, 0, stream>>>(V, Vt);
    k_gemm<DIM, SEQ, 1, 8, 2, 4><<<dim3(512), blk, 0, stream>>>(Vt, Kt, Ws, VtB, KtB, WsB);
    k_split<<<dim3(2048), blk, 0, stream>>>(Q, Qs, 8*SEQ*(DIM/4));
    k_gemm<DIM, DIM, 0, 16, 4, 4><<<dim3(1024), blk, 0, stream>>>(Qs, Ws, Out, QsB, WsB, (size_t)SEQ*DIM);
  } else {
    // per-batch fallback
    u16* Qs = w;
    u16* Kt = Qs + QsB;
    u16* Vt = Kt + KtB;
    u16* Ws = Vt + VtB;
    for (int b = 0; b < BATCH; b++){
      const size_t inOff = (size_t)b * SEQ * DIM;
      k_split<<<dim3(1024), blk, 0, stream>>>(Q + inOff, Qs, SEQ*(DIM/4));
      k_convert_vt<<<dim3(SEQ/32, DIM/32, 1), cblk, 0, stream>>>(K + inOff, Kt);
      k_convert_vt<<<dim3(SEQ/32, DIM/32, 1), cblk, 0, stream>>>(V + inOff, Vt);
      k_gemm<DIM, SEQ, 1, 8, 2, 4><<<dim3(64), blk, 0, stream>>>(Vt, Kt, Ws, VtB, KtB, WsB);
      k_gemm<DIM, DIM, 0, 16, 4, 4><<<dim3(128), blk, 0, stream>>>(Qs, Ws, Out + inOff, QsB, WsB, (size_t)SEQ*DIM);
    }
  }
  k_softmax<<<dim3(BATCH*SEQ), blk, 0, stream>>>(Out);
}